// Round 13
// baseline (426.533 us; speedup 1.0000x reference)
//
#include <hip/hip_runtime.h>

#define T_ 4
#define B_ 64
#define L_ 200
#define H_ 256
#define NH_ 2
#define DH_ 128
#define LCAP 12800

typedef short short8_t __attribute__((ext_vector_type(8)));
typedef float f32x4 __attribute__((ext_vector_type(4)));

#define MFMA_BF16(a, b, c) __builtin_amdgcn_mfma_f32_16x16x32_bf16((a), (b), (c), 0, 0, 0)

__device__ __forceinline__ unsigned short bf16rn(float f) {
  unsigned u = __float_as_uint(f);
  return (unsigned short)((u + 0x7FFFu + ((u >> 16) & 1u)) >> 16);
}
__device__ __forceinline__ float bf16tof(unsigned short h) {
  return __uint_as_float(((unsigned)h) << 16);
}

// 8 spike bytes ({0,1}) -> 8 bf16 ({0,1.0}) packed as short8.
__device__ __forceinline__ short8_t unpack_bf16(uint2 v) {
  union { short8_t s; unsigned u[4]; } r;
  r.u[0] = __builtin_amdgcn_perm(0u, v.x, 0x0C010C00u) * 0x3F80u;
  r.u[1] = __builtin_amdgcn_perm(0u, v.x, 0x0C030C02u) * 0x3F80u;
  r.u[2] = __builtin_amdgcn_perm(0u, v.y, 0x0C010C00u) * 0x3F80u;
  r.u[3] = __builtin_amdgcn_perm(0u, v.y, 0x0C030C02u) * 0x3F80u;
  return r.s;
}

// Pack: wT[mat][k][j] = w[j][k] (f32, for exact fixup), and bf16 3-split B-fragments:
// wf[(((mat*3+s)*16+nt)*8+kc)*512 + lane*8 + j] = split_s(w[nt*16+(lane&15)][kc*32+(lane>>4)*8+j])
// Also zeroes cnt[0..3] (block 0).
__global__ void pack_w(const float* __restrict__ qw, const float* __restrict__ kw,
                       const float* __restrict__ vw, const float* __restrict__ pw,
                       short* __restrict__ wf, float* __restrict__ wT,
                       int* __restrict__ cnt) {
  int id = blockIdx.x * 256 + threadIdx.x;
  if (id < 4) cnt[id] = 0;
  if (id < 262144) {
    int mat = id >> 16, k = (id >> 8) & 255, j = id & 255;
    const float* src = (mat == 0) ? qw : (mat == 1) ? kw : (mat == 2) ? vw : pw;
    wT[id] = src[j * 256 + k];
  }
  int fid = id - 262144;
  if (fid >= 0 && fid < 98304) {
    int lane = fid & 63, kc = (fid >> 6) & 7, nt = (fid >> 9) & 15, ms = fid >> 13;
    int mat = ms / 3, s = ms - mat * 3;
    const float* src = (mat == 0) ? qw : (mat == 1) ? kw : (mat == 2) ? vw : pw;
    int n = nt * 16 + (lane & 15), q = lane >> 4;
    for (int j = 0; j < 8; j++) {
      float v = src[n * 256 + kc * 32 + q * 8 + j];
      unsigned short h1 = bf16rn(v);
      float r1 = v - bf16tof(h1);
      unsigned short h2 = bf16rn(r1);
      float r2 = r1 - bf16tof(h2);
      unsigned short h3 = bf16rn(r2);
      wf[fid * 8 + j] = (short)((s == 0) ? h1 : (s == 1) ? h2 : h3);
    }
  }
}

// A-fragment loads from LDS (same x for all 3 matrices).
#define LOAD_A_QKV(kc, aa0, aa1)                                         \
  do {                                                                   \
    int ap_ = (lane ^ (kc)) * 8;                                         \
    aa0[0] = *(const short8_t*)&sa[(kc) * 512 + ap_];                    \
    aa0[1] = *(const short8_t*)&sa[(8 + (kc)) * 512 + ap_];              \
    aa1[0] = *(const short8_t*)&sa[8192 + (kc) * 512 + ap_];             \
    aa1[1] = *(const short8_t*)&sa[8192 + (8 + (kc)) * 512 + ap_];       \
  } while (0)

// 24 MFMAs per kc step into ONE accumulator: acc += a0b0 + a0b1 + a1b0.
#define QKV_STEP(aa0, aa1, b0a, b1a)                                     \
  do {                                                                   \
    _Pragma("unroll")                                                    \
    for (int jj_ = 0; jj_ < 4; jj_++)                                    \
      _Pragma("unroll")                                                  \
      for (int mt_ = 0; mt_ < 2; mt_++)                                  \
        acc[mt_][jj_] = MFMA_BF16(aa0[mt_], b0a[jj_], acc[mt_][jj_]);    \
    _Pragma("unroll")                                                    \
    for (int jj_ = 0; jj_ < 4; jj_++)                                    \
      _Pragma("unroll")                                                  \
      for (int mt_ = 0; mt_ < 2; mt_++)                                  \
        acc[mt_][jj_] = MFMA_BF16(aa0[mt_], b1a[jj_], acc[mt_][jj_]);    \
    _Pragma("unroll")                                                    \
    for (int jj_ = 0; jj_ < 4; jj_++)                                    \
      _Pragma("unroll")                                                  \
      for (int mt_ = 0; mt_ < 2; mt_++)                                  \
        acc[mt_][jj_] = MFMA_BF16(aa1[mt_], b0a[jj_], acc[mt_][jj_]);    \
  } while (0)

// Fused Q/K/V: merged accumulator + (256,2) - the clean-allocation optimum
// (R11: VGPR=100, FETCH 32/WRITE 38.5, 136.6us). The occupancy axis is
// CLOSED for this kernel: (256,3) and (256,4) spilled in R7/R8/R9/R12
// (true peak pressure in the staging+pingpong region exceeds 128).
__global__ __launch_bounds__(256, 2)
void gemm_qkv(const float* __restrict__ xf, const short* __restrict__ wf,
              const float* __restrict__ qlnw, const float* __restrict__ qlnb,
              const float* __restrict__ klnw, const float* __restrict__ klnb,
              const float* __restrict__ vlnw, const float* __restrict__ vlnb,
              unsigned char* __restrict__ Qsp, unsigned char* __restrict__ Ksp,
              unsigned char* __restrict__ Vsp,
              int* __restrict__ cnt, int* __restrict__ list) {
  __shared__ short sa[2 * 8192];   // [s][mt][kc][slot^(kc&7)][8]
  __shared__ float reds[3][32][4];
  __shared__ float redq[3][32][4];
  __shared__ int pf[24];
  const int tid = threadIdx.x;
  const int w = tid >> 6, lane = tid & 63;
  const int q = lane >> 4, ln = lane & 15;
  const int p0 = blockIdx.x * 8;
  const int jbase = w * 4;

  if (tid < 24) pf[tid] = 0;

  // mat0/kc0 B prefetch -> in flight during staging + barrier
  short8_t bA0[4], bA1[4], bB0[4], bB1[4];
  short8_t aC0[2], aC1[2];
#pragma unroll
  for (int jj = 0; jj < 4; jj++) {
    const short* bp = wf + (size_t)(jbase + jj) * 4096 + lane * 8;
    bA0[jj] = *(const short8_t*)bp;
    bA1[jj] = *(const short8_t*)(bp + 65536);
  }

  // stage: each thread handles 4 chunks of 8 consecutive k in one row
  for (int it = 0; it < 4; it++) {
    int cid = tid + 256 * it;      // 0..1023
    int r = cid >> 5, ck = cid & 31;
    int k0 = ck * 8, kc = ck >> 2, cq = ck & 3;
    int mt = r >> 4, m = r & 15;
    int p = r >> 2, t = r & 3;
    int pi = p0 + p;
    int b = pi / L_, l = pi % L_;
    size_t nrow = ((size_t)t * B_ + b) * L_ + l;
    int base = ((mt * 8 + kc) * 512) + (((cq * 16 + m) ^ (kc & 7)) * 8);
    float4 v0 = *(const float4*)(xf + nrow * H_ + k0);
    float4 v1 = *(const float4*)(xf + nrow * H_ + k0 + 4);
    float f[8] = {v0.x, v0.y, v0.z, v0.w, v1.x, v1.y, v1.z, v1.w};
    union { short8_t v; short s[8]; } H1, H2;
#pragma unroll
    for (int e = 0; e < 8; e++) {
      unsigned short h1 = bf16rn(f[e]);
      float r1 = f[e] - bf16tof(h1);
      unsigned short h2 = bf16rn(r1);
      H1.s[e] = (short)h1; H2.s[e] = (short)h2;
    }
    *(short8_t*)&sa[base] = H1.v;
    *(short8_t*)&sa[base + 8192] = H2.v;
  }
  __syncthreads();

  for (int mat = 0; mat < 3; mat++) {
    const float* lnw = (mat == 0) ? qlnw : (mat == 1) ? klnw : vlnw;
    const float* lnb = (mat == 0) ? qlnb : (mat == 1) ? klnb : vlnb;
    unsigned char* spk = (mat == 0) ? Qsp : (mat == 1) ? Ksp : Vsp;
    const short* wb = wf + (size_t)mat * 196608;

    f32x4 acc[2][4];
#pragma unroll
    for (int mt = 0; mt < 2; mt++)
#pragma unroll
      for (int jj = 0; jj < 4; jj++) {
        f32x4 z = {0.f, 0.f, 0.f, 0.f};
        acc[mt][jj] = z;
      }

#pragma unroll
    for (int kh = 0; kh < 4; kh++) {
      const int kc = 2 * kh;
      // prefetch kc+1 B (issues before kc's MFMAs consume bA)
#pragma unroll
      for (int jj = 0; jj < 4; jj++) {
        const short* bp = wb + (size_t)(kc + 1) * 512 + (size_t)(jbase + jj) * 4096 + lane * 8;
        bB0[jj] = *(const short8_t*)bp;
        bB1[jj] = *(const short8_t*)(bp + 65536);
      }
      LOAD_A_QKV(kc, aC0, aC1);
      QKV_STEP(aC0, aC1, bA0, bA1);
      // prefetch kc+2 (or next matrix's kc0 - flies through the epilogue)
      {
        const short* nx = (kc + 2 < 8) ? (wb + (size_t)(kc + 2) * 512) : (wb + 196608);
#pragma unroll
        for (int jj = 0; jj < 4; jj++) {
          const short* bp = nx + (size_t)(jbase + jj) * 4096 + lane * 8;
          bA0[jj] = *(const short8_t*)bp;
          bA1[jj] = *(const short8_t*)(bp + 65536);
        }
      }
      LOAD_A_QKV(kc + 1, aC0, aC1);
      QKV_STEP(aC0, aC1, bB0, bB1);
    }

    float y[2][4][4];
#pragma unroll
    for (int mt = 0; mt < 2; mt++)
#pragma unroll
      for (int jj = 0; jj < 4; jj++)
#pragma unroll
        for (int i = 0; i < 4; i++)
          y[mt][jj][i] = acc[mt][jj][i];

    // LN stats: single-pass sum + sumsq (row r = mt*16 + 4q + i)
#pragma unroll
    for (int mt = 0; mt < 2; mt++)
#pragma unroll
      for (int i = 0; i < 4; i++) {
        float s = y[mt][0][i] + y[mt][1][i] + y[mt][2][i] + y[mt][3][i];
        float ss = y[mt][0][i] * y[mt][0][i] + y[mt][1][i] * y[mt][1][i]
                 + y[mt][2][i] * y[mt][2][i] + y[mt][3][i] * y[mt][3][i];
#pragma unroll
        for (int o = 1; o < 16; o <<= 1) {
          s += __shfl_xor(s, o, 64);
          ss += __shfl_xor(ss, o, 64);
        }
        if (ln == 0) { reds[mat][16 * mt + 4 * q + i][w] = s; redq[mat][16 * mt + 4 * q + i][w] = ss; }
      }
    __syncthreads();   // stats barrier (the only one per matrix)
    float m_[2][4], rs_[2][4], tolr[2][4];
#pragma unroll
    for (int mt = 0; mt < 2; mt++)
#pragma unroll
      for (int i = 0; i < 4; i++) {
        int r = 16 * mt + 4 * q + i;
        float S = reds[mat][r][0] + reds[mat][r][1] + reds[mat][r][2] + reds[mat][r][3];
        float Q2 = redq[mat][r][0] + redq[mat][r][1] + redq[mat][r][2] + redq[mat][r][3];
        float mm = S * (1.0f / 256.0f);
        float var = Q2 * (1.0f / 256.0f) - mm * mm;
        float rs = 1.0f / sqrtf(var + 1e-5f);
        m_[mt][i] = mm; rs_[mt][i] = rs;
        tolr[mt][i] = 1.75e-4f + 3e-6f * (4.0f + fabsf(mm) * rs);
      }

    // LIF + margin flag
    int fl[2] = {0, 0};
#pragma unroll
    for (int mt = 0; mt < 2; mt++) {
      int pi = p0 + 4 * mt + q;
      int b = pi / L_, l = pi % L_;
#pragma unroll
      for (int jj = 0; jj < 4; jj++) {
        int col = (w * 4 + jj) * 16 + ln;
        float lw = lnw[col], lb = lnb[col];
        float v = 0.0f;
#pragma unroll
        for (int t = 0; t < 4; t++) {
          float yn = (y[mt][jj][t] - m_[mt][t]) * rs_[mt][t] * lw + lb;
          v = (v + yn) * 0.5f;
          bool f = (v >= 1.0f);
          if (fabsf(v - 1.0f) < tolr[mt][t]) fl[mt] = 1;
          int head = col >> 7, d = col & 127;
          spk[((((size_t)t * B_ + b) * NH_ + head) * L_ + l) * DH_ + d] = f ? (unsigned char)1 : (unsigned char)0;
          if (f) v = 0.0f;
        }
      }
    }
#pragma unroll
    for (int o = 1; o < 16; o <<= 1) {
      fl[0] |= __shfl_xor(fl[0], o, 64);
      fl[1] |= __shfl_xor(fl[1], o, 64);
    }
    if (ln == 0) {
      if (fl[0]) atomicOr(&pf[mat * 8 + q], 1);
      if (fl[1]) atomicOr(&pf[mat * 8 + 4 + q], 1);
    }
    // no trailing barrier: per-matrix reds/redq, waves run ahead into mat+1
  }

  __syncthreads();   // pf visibility
  if (tid < 24 && pf[tid]) {
    int mat = tid >> 3, pr = tid & 7;
    int idx = atomicAdd(cnt + mat, 1);
    if (idx < LCAP) list[mat * LCAP + idx] = p0 + pr;
  }
}

#define LOAD_A_PROJ(kc, aa)                                              \
  do {                                                                   \
    int ap_ = (lane ^ (kc)) * 8;                                         \
    aa[0] = *(const short8_t*)&sa[(kc) * 512 + ap_];                     \
    aa[1] = *(const short8_t*)&sa[(8 + (kc)) * 512 + ap_];               \
  } while (0)

// Merged accumulator: acc += a0b0 + a0b1 (16 MFMA/kc, one acc group).
#define PROJ_STEP(aa, b0a, b1a)                                          \
  do {                                                                   \
    _Pragma("unroll")                                                    \
    for (int jj_ = 0; jj_ < 4; jj_++)                                    \
      _Pragma("unroll")                                                  \
      for (int mt_ = 0; mt_ < 2; mt_++)                                  \
        acc[mt_][jj_] = MFMA_BF16(aa[mt_], b0a[jj_], acc[mt_][jj_]);     \
    _Pragma("unroll")                                                    \
    for (int jj_ = 0; jj_ < 4; jj_++)                                    \
      _Pragma("unroll")                                                  \
      for (int mt_ = 0; mt_ < 2; mt_++)                                  \
        acc[mt_][jj_] = MFMA_BF16(aa[mt_], b1a[jj_], acc[mt_][jj_]);     \
  } while (0)

// Proj path: merged accumulator + (256,4) - R12 config (the +21us win;
// smaller footprint than qkv, allocates at 4 blocks/CU).
__global__ __launch_bounds__(256, 4)
void gemm_proj(const unsigned char* __restrict__ xs, const short* __restrict__ wfm,
               const float* __restrict__ bias,
               const float* __restrict__ lnw, const float* __restrict__ lnb,
               float* __restrict__ out,
               int* __restrict__ cnt, int* __restrict__ list) {
  __shared__ short sa[8192];   // [mt][kc][slot^(kc&7)][8]
  __shared__ float reds[32][4];
  __shared__ float redq[32][4];
  __shared__ int pf[8];
  const int tid = threadIdx.x;
  const int w = tid >> 6, lane = tid & 63;
  const int q = lane >> 4, ln = lane & 15;
  const int p0 = blockIdx.x * 8;
  const int jbase = w * 4;

  if (tid < 8) pf[tid] = 0;

  // kc0 B prefetch -> in flight during staging + barrier
  short8_t bA0[4], bA1[4], bB0[4], bB1[4];
  short8_t aC[2], aN[2];
#pragma unroll
  for (int jj = 0; jj < 4; jj++) {
    const short* bp = wfm + (size_t)(jbase + jj) * 4096 + lane * 8;
    bA0[jj] = *(const short8_t*)bp;
    bA1[jj] = *(const short8_t*)(bp + 65536);
  }

  // stage: each thread handles 4 chunks of 8 consecutive k in one row
  for (int it = 0; it < 4; it++) {
    int cid = tid + 256 * it;      // 0..1023
    int r = cid >> 5, ck = cid & 31;
    int k0 = ck * 8, kc = ck >> 2, cq = ck & 3;
    int mt = r >> 4, m = r & 15;
    int p = r >> 2, t = r & 3;
    int pi = p0 + p;
    int b = pi / L_, l = pi % L_;
    size_t nrow = ((size_t)t * B_ + b) * L_ + l;
    int base = ((mt * 8 + kc) * 512) + (((cq * 16 + m) ^ (kc & 7)) * 8);
    uint2 u = *(const uint2*)(xs + nrow * H_ + k0);
    *(short8_t*)&sa[base] = unpack_bf16(u);
  }
  __syncthreads();

  f32x4 acc[2][4];
#pragma unroll
  for (int mt = 0; mt < 2; mt++)
#pragma unroll
    for (int jj = 0; jj < 4; jj++) {
      f32x4 z = {0.f, 0.f, 0.f, 0.f};
      acc[mt][jj] = z;
    }

  LOAD_A_PROJ(0, aC);

#pragma unroll
  for (int kh = 0; kh < 4; kh++) {
    const int kc = 2 * kh;
#pragma unroll
    for (int jj = 0; jj < 4; jj++) {
      const short* bp = wfm + (size_t)(kc + 1) * 512 + (size_t)(jbase + jj) * 4096 + lane * 8;
      bB0[jj] = *(const short8_t*)bp;
      bB1[jj] = *(const short8_t*)(bp + 65536);
    }
    LOAD_A_PROJ(kc + 1, aN);
    PROJ_STEP(aC, bA0, bA1);
    if (kc + 2 < 8) {
#pragma unroll
      for (int jj = 0; jj < 4; jj++) {
        const short* bp = wfm + (size_t)(kc + 2) * 512 + (size_t)(jbase + jj) * 4096 + lane * 8;
        bA0[jj] = *(const short8_t*)bp;
        bA1[jj] = *(const short8_t*)(bp + 65536);
      }
      LOAD_A_PROJ(kc + 2, aC);
    }
    PROJ_STEP(aN, bB0, bB1);
  }

  float y[2][4][4];
#pragma unroll
  for (int mt = 0; mt < 2; mt++)
#pragma unroll
    for (int jj = 0; jj < 4; jj++) {
      float bj = bias[(w * 4 + jj) * 16 + ln];
#pragma unroll
      for (int i = 0; i < 4; i++)
        y[mt][jj][i] = acc[mt][jj][i] + bj;
    }

  // LN stats: single-pass sum + sumsq (row r = mt*16 + 4q + i)
#pragma unroll
  for (int mt = 0; mt < 2; mt++)
#pragma unroll
    for (int i = 0; i < 4; i++) {
      float s = y[mt][0][i] + y[mt][1][i] + y[mt][2][i] + y[mt][3][i];
      float ss = y[mt][0][i] * y[mt][0][i] + y[mt][1][i] * y[mt][1][i]
               + y[mt][2][i] * y[mt][2][i] + y[mt][3][i] * y[mt][3][i];
#pragma unroll
      for (int o = 1; o < 16; o <<= 1) {
        s += __shfl_xor(s, o, 64);
        ss += __shfl_xor(ss, o, 64);
      }
      if (ln == 0) { reds[16 * mt + 4 * q + i][w] = s; redq[16 * mt + 4 * q + i][w] = ss; }
    }
  __syncthreads();
  float m_[2][4], rs_[2][4], tolr[2][4];
#pragma unroll
  for (int mt = 0; mt < 2; mt++)
#pragma unroll
    for (int i = 0; i < 4; i++) {
      int r = 16 * mt + 4 * q + i;
      float S = reds[r][0] + reds[r][1] + reds[r][2] + reds[r][3];
      float Q2 = redq[r][0] + redq[r][1] + redq[r][2] + redq[r][3];
      float mm = S * (1.0f / 256.0f);
      float var = Q2 * (1.0f / 256.0f) - mm * mm;
      float rs = 1.0f / sqrtf(var + 1e-5f);
      m_[mt][i] = mm; rs_[mt][i] = rs;
      tolr[mt][i] = 1.75e-4f + 3e-6f * (4.0f + fabsf(mm) * rs);
    }

  // LIF + margin flag
  int fl[2] = {0, 0};
#pragma unroll
  for (int mt = 0; mt < 2; mt++) {
    int pi = p0 + 4 * mt + q;
    int b = pi / L_, l = pi % L_;
#pragma unroll
    for (int jj = 0; jj < 4; jj++) {
      int col = (w * 4 + jj) * 16 + ln;
      float lw = lnw[col], lb = lnb[col];
      float v = 0.0f;
#pragma unroll
      for (int t = 0; t < 4; t++) {
        float yn = (y[mt][jj][t] - m_[mt][t]) * rs_[mt][t] * lw + lb;
        v = (v + yn) * 0.5f;
        bool f = (v >= 1.0f);
        if (fabsf(v - 1.0f) < tolr[mt][t]) fl[mt] = 1;
        size_t n = ((size_t)t * B_ + b) * L_ + l;
        out[n * H_ + col] = f ? 1.0f : 0.0f;
        if (f) v = 0.0f;
      }
    }
  }
#pragma unroll
  for (int o = 1; o < 16; o <<= 1) {
    fl[0] |= __shfl_xor(fl[0], o, 64);
    fl[1] |= __shfl_xor(fl[1], o, 64);
  }
  if (ln == 0) {
    if (fl[0]) atomicOr(&pf[q], 1);
    if (fl[1]) atomicOr(&pf[4 + q], 1);
  }
  __syncthreads();
  if (tid < 8 && pf[tid]) {
    int idx = atomicAdd(cnt, 1);
    if (idx < LCAP) list[idx] = p0 + tid;
  }
}

// Exact f64 fixup, Q/K/V (R6-passing version, unchanged).
__global__ __launch_bounds__(256)
void fixup_qkv(const float* __restrict__ xf, const float* __restrict__ wT,
               const float* __restrict__ qlnw, const float* __restrict__ qlnb,
               const float* __restrict__ klnw, const float* __restrict__ klnb,
               const float* __restrict__ vlnw, const float* __restrict__ vlnb,
               unsigned char* __restrict__ Qsp, unsigned char* __restrict__ Ksp,
               unsigned char* __restrict__ Vsp,
               const int* __restrict__ cnt, const int* __restrict__ list) {
  __shared__ float sx[4][256];     // 4 KB: the pair's 4 t-rows
  __shared__ double rsum[4][4];    // [wave][t]
  __shared__ double mv[4], rsd[4];
  const int tid = threadIdx.x;
  const int w = tid >> 6, lane = tid & 63;
  int n0 = cnt[0]; if (n0 > LCAP) n0 = LCAP;
  int n1 = cnt[1]; if (n1 > LCAP) n1 = LCAP;
  int n2 = cnt[2]; if (n2 > LCAP) n2 = LCAP;
  int ntot = n0 + n1 + n2;
  for (int e = blockIdx.x; e < ntot; e += gridDim.x) {
    int mat, ei;
    if (e < n0) { mat = 0; ei = e; }
    else if (e < n0 + n1) { mat = 1; ei = e - n0; }
    else { mat = 2; ei = e - n0 - n1; }
    const float* wTm = wT + (size_t)mat * 65536;
    const float* lnw = (mat == 0) ? qlnw : (mat == 1) ? klnw : vlnw;
    const float* lnb = (mat == 0) ? qlnb : (mat == 1) ? klnb : vlnb;
    unsigned char* spk = (mat == 0) ? Qsp : (mat == 1) ? Ksp : Vsp;
    int pi = list[mat * LCAP + ei];
    int b = pi / L_, l = pi % L_;

    // stage: wave w loads t-row w (64 lanes x float4 = 256 floats, coalesced)
    {
      size_t nrow = ((size_t)w * B_ + b) * L_ + l;
      float4 v = *(const float4*)(xf + nrow * H_ + lane * 4);
      *(float4*)&sx[w][lane * 4] = v;
    }
    __syncthreads();

    double acc[4] = {0.0, 0.0, 0.0, 0.0};
    for (int k = 0; k < 256; k++) {
      double wv = (double)wTm[k * 256 + tid];
      acc[0] += (double)sx[0][k] * wv;
      acc[1] += (double)sx[1][k] * wv;
      acc[2] += (double)sx[2][k] * wv;
      acc[3] += (double)sx[3][k] * wv;
    }
#pragma unroll
    for (int t = 0; t < 4; t++) {
      double s = acc[t];
#pragma unroll
      for (int o = 1; o < 64; o <<= 1) s += __shfl_xor(s, o, 64);
      if (lane == 0) rsum[w][t] = s;
    }
    __syncthreads();
    if (tid < 4) mv[tid] = (rsum[0][tid] + rsum[1][tid] + rsum[2][tid] + rsum[3][tid]) * (1.0 / 256.0);
    __syncthreads();
#pragma unroll
    for (int t = 0; t < 4; t++) {
      double d = acc[t] - mv[t];
      double ss = d * d;
#pragma unroll
      for (int o = 1; o < 64; o <<= 1) ss += __shfl_xor(ss, o, 64);
      if (lane == 0) rsum[w][t] = ss;
    }
    __syncthreads();
    if (tid < 4) {
      double var = (rsum[0][tid] + rsum[1][tid] + rsum[2][tid] + rsum[3][tid]) * (1.0 / 256.0);
      rsd[tid] = 1.0 / sqrt(var + 1e-5);
    }
    __syncthreads();
    double lw = (double)lnw[tid], lb = (double)lnb[tid];
    int head = tid >> 7, d = tid & 127;
    double v = 0.0;
#pragma unroll
    for (int t = 0; t < 4; t++) {
      double yn = (acc[t] - mv[t]) * rsd[t] * lw + lb;
      v = (v + yn) * 0.5;
      bool f = (v >= 1.0);
      spk[((((size_t)t * B_ + b) * NH_ + head) * L_ + l) * DH_ + d] = f ? (unsigned char)1 : (unsigned char)0;
      if (f) v = 0.0;
    }
    __syncthreads();   // sx/rsum reuse fence before next pair
  }
}

// Exact f64 fixup, proj (R6-passing version, unchanged).
__global__ __launch_bounds__(256)
void fixup_proj(const unsigned char* __restrict__ xs, const float* __restrict__ wT,
                const float* __restrict__ bias,
                const float* __restrict__ lnw, const float* __restrict__ lnb,
                float* __restrict__ out,
                const int* __restrict__ cnt, const int* __restrict__ list) {
  __shared__ float sx[4][256];
  __shared__ double rsum[4][4];
  __shared__ double mv[4], rsd[4];
  const int tid = threadIdx.x;
  const int w = tid >> 6, lane = tid & 63;
  int n = *cnt; if (n > LCAP) n = LCAP;
  for (int e = blockIdx.x; e < n; e += gridDim.x) {
    int pi = list[e];
    int b = pi / L_, l = pi % L_;
    size_t nrowW = ((size_t)w * B_ + b) * L_ + l;

    // stage: wave w loads t-row w (64 lanes x uchar4 = 256 u8, converted)
    {
      uchar4 u = *(const uchar4*)(xs + nrowW * H_ + lane * 4);
      float4 v = make_float4((float)u.x, (float)u.y, (float)u.z, (float)u.w);
      *(float4*)&sx[w][lane * 4] = v;
    }
    __syncthreads();

    double acc[4];
    double bj = (double)bias[tid];
#pragma unroll
    for (int t = 0; t < 4; t++) acc[t] = bj;
    for (int k = 0; k < 256; k++) {
      double wv = (double)wT[k * 256 + tid];
      acc[0] += (double)sx[0][k] * wv;
      acc[1] += (double)sx[1][k] * wv;
      acc[2] += (double)sx[2][k] * wv;
      acc[3] += (double)sx[3][k] * wv;
    }
#pragma unroll
    for (int t = 0; t < 4; t++) {
      double s = acc[t];
#pragma unroll
      for (int o = 1; o < 64; o <<= 1) s += __shfl_xor(s, o, 64);
      if (lane == 0) rsum[w][t] = s;
    }
    __syncthreads();
    if (tid < 4) mv[tid] = (rsum[0][tid] + rsum[1][tid] + rsum[2][tid] + rsum[3][tid]) * (1.0 / 256.0);
    __syncthreads();
#pragma unroll
    for (int t = 0; t < 4; t++) {
      double d = acc[t] - mv[t];
      double ss = d * d;
#pragma unroll
      for (int o = 1; o < 64; o <<= 1) ss += __shfl_xor(ss, o, 64);
      if (lane == 0) rsum[w][t] = ss;
    }
    __syncthreads();
    if (tid < 4) {
      double var = (rsum[0][tid] + rsum[1][tid] + rsum[2][tid] + rsum[3][tid]) * (1.0 / 256.0);
      rsd[tid] = 1.0 / sqrt(var + 1e-5);
    }
    __syncthreads();
    double lw = (double)lnw[tid], lb = (double)lnb[tid];
    double v = 0.0;
#pragma unroll
    for (int t = 0; t < 4; t++) {
      double yn = (acc[t] - mv[t]) * rsd[t] * lw + lb;
      v = (v + yn) * 0.5;
      bool f = (v >= 1.0);
      out[(((size_t)t * B_ + b) * L_ + l) * H_ + tid] = f ? 1.0f : 0.0f;
      if (f) v = 0.0;
    }
    __syncthreads();
  }
}

// V spikes [slab][m<200][d] u8 -> Vt [slab][d][m<224] u8, zero-padded m>=200.
__global__ __launch_bounds__(256)
void vt_prep(const unsigned char* __restrict__ Vs, unsigned char* __restrict__ Vt) {
  const int slab = blockIdx.x;
  const int w = threadIdx.x >> 6, lane = threadIdx.x & 63;
  const unsigned char* src = Vs + (size_t)slab * (L_ * DH_);
  unsigned char* dst = Vt + (size_t)slab * (DH_ * 224);
  for (int d = w; d < DH_; d += 4) {
    for (int mb = 0; mb < 4; mb++) {
      int m = mb * 64 + lane;
      unsigned char v = 0;
      if (m < L_) v = src[(size_t)m * DH_ + d];
      if (m < 224) dst[(size_t)d * 224 + m] = v;
    }
  }
}

// MFMA attention + attn-LIF(v_th=0.5). Exact (spikes {0,1}, dots <=128, sums <=25600).
__global__ __launch_bounds__(256)
void attn_mfma(const unsigned char* __restrict__ Qs, const unsigned char* __restrict__ Ks,
               const unsigned char* __restrict__ Vt, unsigned char* __restrict__ S2) {
  __shared__ unsigned short sS[32 * 232];
  const int tid = threadIdx.x;
  const int w = tid >> 6, lane = tid & 63;
  const int quad = lane >> 4, ln = lane & 15;
  const int bid = blockIdx.x;
  const int lt = bid % 7;
  const int head = (bid / 7) & 1;
  const int b = bid / 14;
  const int l0 = lt * 32;

  for (int i = tid; i < 32 * 232; i += 256) sS[i] = 0;

  float vmem[2][2][4];
#pragma unroll
  for (int di = 0; di < 2; di++)
#pragma unroll
    for (int ls = 0; ls < 2; ls++)
#pragma unroll
      for (int r = 0; r < 4; r++) vmem[di][ls][r] = 0.f;

  __syncthreads();

  for (int t = 0; t < T_; t++) {
    const int slab = (t * B_ + b) * NH_ + head;
    const unsigned char* qb = Qs + (size_t)slab * (L_ * DH_) + (size_t)l0 * DH_;
    const unsigned char* kb = Ks + (size_t)slab * (L_ * DH_);

    short8_t af[2][4];
#pragma unroll
    for (int ls = 0; ls < 2; ls++)
#pragma unroll
      for (int ks = 0; ks < 4; ks++)
        af[ls][ks] = unpack_bf16(*(const uint2*)(qb + (size_t)(ls * 16 + ln) * DH_ + ks * 32 + quad * 8));

#pragma unroll
    for (int i = 0; i < 4; i++) {
      int nt = w + 4 * i;
      if (nt < 13) {
        short8_t bf[4];
#pragma unroll
        for (int ks = 0; ks < 4; ks++)
          bf[ks] = unpack_bf16(*(const uint2*)(kb + (size_t)(nt * 16 + ln) * DH_ + ks * 32 + quad * 8));
#pragma unroll
        for (int ls = 0; ls < 2; ls++) {
          f32x4 acc = {0.f, 0.f, 0.f, 0.f};
#pragma unroll
          for (int ks = 0; ks < 4; ks++)
            acc = MFMA_BF16(af[ls][ks], bf[ks], acc);
#pragma unroll
          for (int r = 0; r < 4; r++)
            sS[(ls * 16 + quad * 4 + r) * 232 + nt * 16 + ln] =
                (unsigned short)(__float_as_uint(acc[r]) >> 16);
        }
      }
    }
    __syncthreads();

    const unsigned char* vb = Vt + (size_t)slab * (DH_ * 224);
    f32x4 a2[2][2];
#pragma unroll
    for (int di = 0; di < 2; di++)
#pragma unroll
      for (int ls = 0; ls < 2; ls++) { f32x4 z = {0.f, 0.f, 0.f, 0.f}; a2[di][ls] = z; }

#pragma unroll
    for (int ks = 0; ks < 7; ks++) {
      short8_t s0 = *(const short8_t*)&sS[(0 * 16 + ln) * 232 + ks * 32 + quad * 8];
      short8_t s1 = *(const short8_t*)&sS[(1 * 16 + ln) * 232 + ks * 32 + quad * 8];
#pragma unroll
      for (int di = 0; di < 2; di++) {
        int dt = w + 4 * di;
        short8_t bv = unpack_bf16(*(const uint2*)(vb + (size_t)(dt * 16 + ln) * 224 + ks * 32 + quad * 8));
        a2[di][0] = MFMA_BF16(s0, bv, a2[di][0]);
        a2[di][1] = MFMA_BF16(s1, bv, a2[di][1]);
      }
    }

#pragma unroll
    for (int di = 0; di < 2; di++)
#pragma unroll
      for (int ls = 0; ls < 2; ls++)
#pragma unroll
        for (int r = 0; r < 4; r++) {
          float y = a2[di][ls][r] * 0.125f;
          float v = (vmem[di][ls][r] + y) * 0.5f;
          bool f = (v >= 0.5f);
          int l = l0 + ls * 16 + quad * 4 + r;
          if (l < L_)
            S2[(((size_t)t * B_ + b) * L_ + l) * H_ + head * DH_ + (w + 4 * di) * 16 + ln] =
                f ? (unsigned char)1 : (unsigned char)0;
          vmem[di][ls][r] = f ? 0.f : v;
        }
    __syncthreads();
  }
}

extern "C" void kernel_launch(void* const* d_in, const int* in_sizes, int n_in,
                              void* d_out, int out_size, void* d_ws, size_t ws_size,
                              hipStream_t stream) {
  (void)in_sizes; (void)n_in; (void)out_size; (void)ws_size;
  const float* x    = (const float*)d_in[0];
  const float* qw   = (const float*)d_in[1];
  const float* qlnw = (const float*)d_in[2];
  const float* qlnb = (const float*)d_in[3];
  const float* kw   = (const float*)d_in[4];
  const float* klnw = (const float*)d_in[5];
  const float* klnb = (const float*)d_in[6];
  const float* vw   = (const float*)d_in[7];
  const float* vlnw = (const float*)d_in[8];
  const float* vlnb = (const float*)d_in[9];
  const float* pw   = (const float*)d_in[10];
  const float* pb   = (const float*)d_in[11];
  const float* plnw = (const float*)d_in[12];
  const float* plnb = (const float*)d_in[13];

  char* ws = (char*)d_ws;
  const size_t SPK = (size_t)T_ * B_ * NH_ * L_ * DH_;     // 13,107,200
  short* wf  = (short*)ws;                                  // 1,572,864 B
  float* wT  = (float*)(ws + 1572864);                      // 1,048,576 B
  int*  cnt  = (int*)(ws + 2621440);                        // 16 B
  int*  list = (int*)(ws + 2621696);                        // 204,800 B
  unsigned char* Qsp = (unsigned char*)(ws + 2826496);
  unsigned char* Ksp = Qsp + SPK;
  unsigned char* Vsp = Ksp + SPK;
  unsigned char* S2  = Vsp;                                 // alias after vt_prep
  unsigned char* Vt  = Vsp + SPK;                           // ~54.2 MiB total

  hipLaunchKernelGGL(pack_w, dim3(1408), dim3(256), 0, stream, qw, kw, vw, pw, wf, wT, cnt);

  hipLaunchKernelGGL(gemm_qkv, dim3(1600), dim3(256), 0, stream,
                     x, wf, qlnw, qlnb, klnw, klnb, vlnw, vlnb, Qsp, Ksp, Vsp, cnt, list);

  hipLaunchKernelGGL(fixup_qkv, dim3(2048), dim3(256), 0, stream,
                     x, wT, qlnw, qlnb, klnw, klnb, vlnw, vlnb, Qsp, Ksp, Vsp, cnt, list);

  hipLaunchKernelGGL(vt_prep, dim3(512), dim3(256), 0, stream, Vsp, Vt);
  hipLaunchKernelGGL(attn_mfma, dim3(896), dim3(256), 0, stream, Qsp, Ksp, Vt, S2);

  hipLaunchKernelGGL(gemm_proj, dim3(1600), dim3(256), 0, stream,
                     S2, wf + 589824, pb, plnw, plnb, (float*)d_out, cnt + 3, list + 3 * LCAP);
  hipLaunchKernelGGL(fixup_proj, dim3(2048), dim3(256), 0, stream,
                     S2, wT + 196608, pb, plnw, plnb, (float*)d_out, cnt + 3, list + 3 * LCAP);
}

// Round 14
// 412.386 us; speedup vs baseline: 1.0343x; 1.0343x over previous
//
#include <hip/hip_runtime.h>

#define T_ 4
#define B_ 64
#define L_ 200
#define H_ 256
#define NH_ 2
#define DH_ 128
#define LCAP 12800

typedef short short8_t __attribute__((ext_vector_type(8)));
typedef float f32x4 __attribute__((ext_vector_type(4)));
typedef int i32x4 __attribute__((ext_vector_type(4)));

#define MFMA_BF16(a, b, c) __builtin_amdgcn_mfma_f32_16x16x32_bf16((a), (b), (c), 0, 0, 0)
#define MFMA_I8(a, b, c) __builtin_amdgcn_mfma_i32_16x16x64_i8((a), (b), (c), 0, 0, 0)

__device__ __forceinline__ unsigned short bf16rn(float f) {
  unsigned u = __float_as_uint(f);
  return (unsigned short)((u + 0x7FFFu + ((u >> 16) & 1u)) >> 16);
}
__device__ __forceinline__ float bf16tof(unsigned short h) {
  return __uint_as_float(((unsigned)h) << 16);
}

// 8 spike bytes ({0,1}) -> 8 bf16 ({0,1.0}) packed as short8.
__device__ __forceinline__ short8_t unpack_bf16(uint2 v) {
  union { short8_t s; unsigned u[4]; } r;
  r.u[0] = __builtin_amdgcn_perm(0u, v.x, 0x0C010C00u) * 0x3F80u;
  r.u[1] = __builtin_amdgcn_perm(0u, v.x, 0x0C030C02u) * 0x3F80u;
  r.u[2] = __builtin_amdgcn_perm(0u, v.y, 0x0C010C00u) * 0x3F80u;
  r.u[3] = __builtin_amdgcn_perm(0u, v.y, 0x0C030C02u) * 0x3F80u;
  return r.s;
}

// Pack: wT[mat][k][j] = w[j][k] (f32, for exact fixup), and bf16 3-split B-fragments:
// wf[(((mat*3+s)*16+nt)*8+kc)*512 + lane*8 + j] = split_s(w[nt*16+(lane&15)][kc*32+(lane>>4)*8+j])
// Also zeroes cnt[0..3] (block 0).
__global__ void pack_w(const float* __restrict__ qw, const float* __restrict__ kw,
                       const float* __restrict__ vw, const float* __restrict__ pw,
                       short* __restrict__ wf, float* __restrict__ wT,
                       int* __restrict__ cnt) {
  int id = blockIdx.x * 256 + threadIdx.x;
  if (id < 4) cnt[id] = 0;
  if (id < 262144) {
    int mat = id >> 16, k = (id >> 8) & 255, j = id & 255;
    const float* src = (mat == 0) ? qw : (mat == 1) ? kw : (mat == 2) ? vw : pw;
    wT[id] = src[j * 256 + k];
  }
  int fid = id - 262144;
  if (fid >= 0 && fid < 98304) {
    int lane = fid & 63, kc = (fid >> 6) & 7, nt = (fid >> 9) & 15, ms = fid >> 13;
    int mat = ms / 3, s = ms - mat * 3;
    const float* src = (mat == 0) ? qw : (mat == 1) ? kw : (mat == 2) ? vw : pw;
    int n = nt * 16 + (lane & 15), q = lane >> 4;
    for (int j = 0; j < 8; j++) {
      float v = src[n * 256 + kc * 32 + q * 8 + j];
      unsigned short h1 = bf16rn(v);
      float r1 = v - bf16tof(h1);
      unsigned short h2 = bf16rn(r1);
      float r2 = r1 - bf16tof(h2);
      unsigned short h3 = bf16rn(r2);
      wf[fid * 8 + j] = (short)((s == 0) ? h1 : (s == 1) ? h2 : h3);
    }
  }
}

// A-fragment loads from LDS (same x for all 3 matrices).
#define LOAD_A_QKV(kc, aa0, aa1)                                         \
  do {                                                                   \
    int ap_ = (lane ^ (kc)) * 8;                                         \
    aa0[0] = *(const short8_t*)&sa[(kc) * 512 + ap_];                    \
    aa0[1] = *(const short8_t*)&sa[(8 + (kc)) * 512 + ap_];              \
    aa1[0] = *(const short8_t*)&sa[8192 + (kc) * 512 + ap_];             \
    aa1[1] = *(const short8_t*)&sa[8192 + (8 + (kc)) * 512 + ap_];       \
  } while (0)

// 24 MFMAs per kc step into ONE accumulator: acc += a0b0 + a0b1 + a1b0.
#define QKV_STEP(aa0, aa1, b0a, b1a)                                     \
  do {                                                                   \
    _Pragma("unroll")                                                    \
    for (int jj_ = 0; jj_ < 4; jj_++)                                    \
      _Pragma("unroll")                                                  \
      for (int mt_ = 0; mt_ < 2; mt_++)                                  \
        acc[mt_][jj_] = MFMA_BF16(aa0[mt_], b0a[jj_], acc[mt_][jj_]);    \
    _Pragma("unroll")                                                    \
    for (int jj_ = 0; jj_ < 4; jj_++)                                    \
      _Pragma("unroll")                                                  \
      for (int mt_ = 0; mt_ < 2; mt_++)                                  \
        acc[mt_][jj_] = MFMA_BF16(aa0[mt_], b1a[jj_], acc[mt_][jj_]);    \
    _Pragma("unroll")                                                    \
    for (int jj_ = 0; jj_ < 4; jj_++)                                    \
      _Pragma("unroll")                                                  \
      for (int mt_ = 0; mt_ < 2; mt_++)                                  \
        acc[mt_][jj_] = MFMA_BF16(aa1[mt_], b0a[jj_], acc[mt_][jj_]);    \
  } while (0)

// Fused Q/K/V: merged accumulator + (256,2) - the clean-allocation optimum
// (VGPR=100, FETCH 32/WRITE 38.5, 136.6us). Occupancy axis CLOSED: (256,3)
// and (256,4) spill (R7/R8/R9/R12).
__global__ __launch_bounds__(256, 2)
void gemm_qkv(const float* __restrict__ xf, const short* __restrict__ wf,
              const float* __restrict__ qlnw, const float* __restrict__ qlnb,
              const float* __restrict__ klnw, const float* __restrict__ klnb,
              const float* __restrict__ vlnw, const float* __restrict__ vlnb,
              unsigned char* __restrict__ Qsp, unsigned char* __restrict__ Ksp,
              unsigned char* __restrict__ Vsp,
              int* __restrict__ cnt, int* __restrict__ list) {
  __shared__ short sa[2 * 8192];   // [s][mt][kc][slot^(kc&7)][8]
  __shared__ float reds[3][32][4];
  __shared__ float redq[3][32][4];
  __shared__ int pf[24];
  const int tid = threadIdx.x;
  const int w = tid >> 6, lane = tid & 63;
  const int q = lane >> 4, ln = lane & 15;
  const int p0 = blockIdx.x * 8;
  const int jbase = w * 4;

  if (tid < 24) pf[tid] = 0;

  // mat0/kc0 B prefetch -> in flight during staging + barrier
  short8_t bA0[4], bA1[4], bB0[4], bB1[4];
  short8_t aC0[2], aC1[2];
#pragma unroll
  for (int jj = 0; jj < 4; jj++) {
    const short* bp = wf + (size_t)(jbase + jj) * 4096 + lane * 8;
    bA0[jj] = *(const short8_t*)bp;
    bA1[jj] = *(const short8_t*)(bp + 65536);
  }

  // stage: each thread handles 4 chunks of 8 consecutive k in one row
  for (int it = 0; it < 4; it++) {
    int cid = tid + 256 * it;      // 0..1023
    int r = cid >> 5, ck = cid & 31;
    int k0 = ck * 8, kc = ck >> 2, cq = ck & 3;
    int mt = r >> 4, m = r & 15;
    int p = r >> 2, t = r & 3;
    int pi = p0 + p;
    int b = pi / L_, l = pi % L_;
    size_t nrow = ((size_t)t * B_ + b) * L_ + l;
    int base = ((mt * 8 + kc) * 512) + (((cq * 16 + m) ^ (kc & 7)) * 8);
    float4 v0 = *(const float4*)(xf + nrow * H_ + k0);
    float4 v1 = *(const float4*)(xf + nrow * H_ + k0 + 4);
    float f[8] = {v0.x, v0.y, v0.z, v0.w, v1.x, v1.y, v1.z, v1.w};
    union { short8_t v; short s[8]; } H1, H2;
#pragma unroll
    for (int e = 0; e < 8; e++) {
      unsigned short h1 = bf16rn(f[e]);
      float r1 = f[e] - bf16tof(h1);
      unsigned short h2 = bf16rn(r1);
      H1.s[e] = (short)h1; H2.s[e] = (short)h2;
    }
    *(short8_t*)&sa[base] = H1.v;
    *(short8_t*)&sa[base + 8192] = H2.v;
  }
  __syncthreads();

  for (int mat = 0; mat < 3; mat++) {
    const float* lnw = (mat == 0) ? qlnw : (mat == 1) ? klnw : vlnw;
    const float* lnb = (mat == 0) ? qlnb : (mat == 1) ? klnb : vlnb;
    unsigned char* spk = (mat == 0) ? Qsp : (mat == 1) ? Ksp : Vsp;
    const short* wb = wf + (size_t)mat * 196608;

    f32x4 acc[2][4];
#pragma unroll
    for (int mt = 0; mt < 2; mt++)
#pragma unroll
      for (int jj = 0; jj < 4; jj++) {
        f32x4 z = {0.f, 0.f, 0.f, 0.f};
        acc[mt][jj] = z;
      }

#pragma unroll
    for (int kh = 0; kh < 4; kh++) {
      const int kc = 2 * kh;
      // prefetch kc+1 B (issues before kc's MFMAs consume bA)
#pragma unroll
      for (int jj = 0; jj < 4; jj++) {
        const short* bp = wb + (size_t)(kc + 1) * 512 + (size_t)(jbase + jj) * 4096 + lane * 8;
        bB0[jj] = *(const short8_t*)bp;
        bB1[jj] = *(const short8_t*)(bp + 65536);
      }
      LOAD_A_QKV(kc, aC0, aC1);
      QKV_STEP(aC0, aC1, bA0, bA1);
      // prefetch kc+2 (or next matrix's kc0 - flies through the epilogue)
      {
        const short* nx = (kc + 2 < 8) ? (wb + (size_t)(kc + 2) * 512) : (wb + 196608);
#pragma unroll
        for (int jj = 0; jj < 4; jj++) {
          const short* bp = nx + (size_t)(jbase + jj) * 4096 + lane * 8;
          bA0[jj] = *(const short8_t*)bp;
          bA1[jj] = *(const short8_t*)(bp + 65536);
        }
      }
      LOAD_A_QKV(kc + 1, aC0, aC1);
      QKV_STEP(aC0, aC1, bB0, bB1);
    }

    float y[2][4][4];
#pragma unroll
    for (int mt = 0; mt < 2; mt++)
#pragma unroll
      for (int jj = 0; jj < 4; jj++)
#pragma unroll
        for (int i = 0; i < 4; i++)
          y[mt][jj][i] = acc[mt][jj][i];

    // LN stats: single-pass sum + sumsq (row r = mt*16 + 4q + i)
#pragma unroll
    for (int mt = 0; mt < 2; mt++)
#pragma unroll
      for (int i = 0; i < 4; i++) {
        float s = y[mt][0][i] + y[mt][1][i] + y[mt][2][i] + y[mt][3][i];
        float ss = y[mt][0][i] * y[mt][0][i] + y[mt][1][i] * y[mt][1][i]
                 + y[mt][2][i] * y[mt][2][i] + y[mt][3][i] * y[mt][3][i];
#pragma unroll
        for (int o = 1; o < 16; o <<= 1) {
          s += __shfl_xor(s, o, 64);
          ss += __shfl_xor(ss, o, 64);
        }
        if (ln == 0) { reds[mat][16 * mt + 4 * q + i][w] = s; redq[mat][16 * mt + 4 * q + i][w] = ss; }
      }
    __syncthreads();   // stats barrier (the only one per matrix)
    float m_[2][4], rs_[2][4], tolr[2][4];
#pragma unroll
    for (int mt = 0; mt < 2; mt++)
#pragma unroll
      for (int i = 0; i < 4; i++) {
        int r = 16 * mt + 4 * q + i;
        float S = reds[mat][r][0] + reds[mat][r][1] + reds[mat][r][2] + reds[mat][r][3];
        float Q2 = redq[mat][r][0] + redq[mat][r][1] + redq[mat][r][2] + redq[mat][r][3];
        float mm = S * (1.0f / 256.0f);
        float var = Q2 * (1.0f / 256.0f) - mm * mm;
        float rs = 1.0f / sqrtf(var + 1e-5f);
        m_[mt][i] = mm; rs_[mt][i] = rs;
        tolr[mt][i] = 1.75e-4f + 3e-6f * (4.0f + fabsf(mm) * rs);
      }

    // LIF + margin flag
    int fl[2] = {0, 0};
#pragma unroll
    for (int mt = 0; mt < 2; mt++) {
      int pi = p0 + 4 * mt + q;
      int b = pi / L_, l = pi % L_;
#pragma unroll
      for (int jj = 0; jj < 4; jj++) {
        int col = (w * 4 + jj) * 16 + ln;
        float lw = lnw[col], lb = lnb[col];
        float v = 0.0f;
#pragma unroll
        for (int t = 0; t < 4; t++) {
          float yn = (y[mt][jj][t] - m_[mt][t]) * rs_[mt][t] * lw + lb;
          v = (v + yn) * 0.5f;
          bool f = (v >= 1.0f);
          if (fabsf(v - 1.0f) < tolr[mt][t]) fl[mt] = 1;
          int head = col >> 7, d = col & 127;
          spk[((((size_t)t * B_ + b) * NH_ + head) * L_ + l) * DH_ + d] = f ? (unsigned char)1 : (unsigned char)0;
          if (f) v = 0.0f;
        }
      }
    }
#pragma unroll
    for (int o = 1; o < 16; o <<= 1) {
      fl[0] |= __shfl_xor(fl[0], o, 64);
      fl[1] |= __shfl_xor(fl[1], o, 64);
    }
    if (ln == 0) {
      if (fl[0]) atomicOr(&pf[mat * 8 + q], 1);
      if (fl[1]) atomicOr(&pf[mat * 8 + 4 + q], 1);
    }
    // no trailing barrier: per-matrix reds/redq, waves run ahead into mat+1
  }

  __syncthreads();   // pf visibility
  if (tid < 24 && pf[tid]) {
    int mat = tid >> 3, pr = tid & 7;
    int idx = atomicAdd(cnt + mat, 1);
    if (idx < LCAP) list[mat * LCAP + idx] = p0 + pr;
  }
}

#define LOAD_A_PROJ(kc, aa)                                              \
  do {                                                                   \
    int ap_ = (lane ^ (kc)) * 8;                                         \
    aa[0] = *(const short8_t*)&sa[(kc) * 512 + ap_];                     \
    aa[1] = *(const short8_t*)&sa[(8 + (kc)) * 512 + ap_];               \
  } while (0)

// Merged accumulator: acc += a0b0 + a0b1 (16 MFMA/kc, one acc group).
#define PROJ_STEP(aa, b0a, b1a)                                          \
  do {                                                                   \
    _Pragma("unroll")                                                    \
    for (int jj_ = 0; jj_ < 4; jj_++)                                    \
      _Pragma("unroll")                                                  \
      for (int mt_ = 0; mt_ < 2; mt_++)                                  \
        acc[mt_][jj_] = MFMA_BF16(aa[mt_], b0a[jj_], acc[mt_][jj_]);     \
    _Pragma("unroll")                                                    \
    for (int jj_ = 0; jj_ < 4; jj_++)                                    \
      _Pragma("unroll")                                                  \
      for (int mt_ = 0; mt_ < 2; mt_++)                                  \
        acc[mt_][jj_] = MFMA_BF16(aa[mt_], b1a[jj_], acc[mt_][jj_]);     \
  } while (0)

// Proj path: merged accumulator + (256,4) (best measured config).
__global__ __launch_bounds__(256, 4)
void gemm_proj(const unsigned char* __restrict__ xs, const short* __restrict__ wfm,
               const float* __restrict__ bias,
               const float* __restrict__ lnw, const float* __restrict__ lnb,
               float* __restrict__ out,
               int* __restrict__ cnt, int* __restrict__ list) {
  __shared__ short sa[8192];   // [mt][kc][slot^(kc&7)][8]
  __shared__ float reds[32][4];
  __shared__ float redq[32][4];
  __shared__ int pf[8];
  const int tid = threadIdx.x;
  const int w = tid >> 6, lane = tid & 63;
  const int q = lane >> 4, ln = lane & 15;
  const int p0 = blockIdx.x * 8;
  const int jbase = w * 4;

  if (tid < 8) pf[tid] = 0;

  // kc0 B prefetch -> in flight during staging + barrier
  short8_t bA0[4], bA1[4], bB0[4], bB1[4];
  short8_t aC[2], aN[2];
#pragma unroll
  for (int jj = 0; jj < 4; jj++) {
    const short* bp = wfm + (size_t)(jbase + jj) * 4096 + lane * 8;
    bA0[jj] = *(const short8_t*)bp;
    bA1[jj] = *(const short8_t*)(bp + 65536);
  }

  // stage: each thread handles 4 chunks of 8 consecutive k in one row
  for (int it = 0; it < 4; it++) {
    int cid = tid + 256 * it;      // 0..1023
    int r = cid >> 5, ck = cid & 31;
    int k0 = ck * 8, kc = ck >> 2, cq = ck & 3;
    int mt = r >> 4, m = r & 15;
    int p = r >> 2, t = r & 3;
    int pi = p0 + p;
    int b = pi / L_, l = pi % L_;
    size_t nrow = ((size_t)t * B_ + b) * L_ + l;
    int base = ((mt * 8 + kc) * 512) + (((cq * 16 + m) ^ (kc & 7)) * 8);
    uint2 u = *(const uint2*)(xs + nrow * H_ + k0);
    *(short8_t*)&sa[base] = unpack_bf16(u);
  }
  __syncthreads();

  f32x4 acc[2][4];
#pragma unroll
  for (int mt = 0; mt < 2; mt++)
#pragma unroll
    for (int jj = 0; jj < 4; jj++) {
      f32x4 z = {0.f, 0.f, 0.f, 0.f};
      acc[mt][jj] = z;
    }

  LOAD_A_PROJ(0, aC);

#pragma unroll
  for (int kh = 0; kh < 4; kh++) {
    const int kc = 2 * kh;
#pragma unroll
    for (int jj = 0; jj < 4; jj++) {
      const short* bp = wfm + (size_t)(kc + 1) * 512 + (size_t)(jbase + jj) * 4096 + lane * 8;
      bB0[jj] = *(const short8_t*)bp;
      bB1[jj] = *(const short8_t*)(bp + 65536);
    }
    LOAD_A_PROJ(kc + 1, aN);
    PROJ_STEP(aC, bA0, bA1);
    if (kc + 2 < 8) {
#pragma unroll
      for (int jj = 0; jj < 4; jj++) {
        const short* bp = wfm + (size_t)(kc + 2) * 512 + (size_t)(jbase + jj) * 4096 + lane * 8;
        bA0[jj] = *(const short8_t*)bp;
        bA1[jj] = *(const short8_t*)(bp + 65536);
      }
      LOAD_A_PROJ(kc + 2, aC);
    }
    PROJ_STEP(aN, bB0, bB1);
  }

  float y[2][4][4];
#pragma unroll
  for (int mt = 0; mt < 2; mt++)
#pragma unroll
    for (int jj = 0; jj < 4; jj++) {
      float bj = bias[(w * 4 + jj) * 16 + ln];
#pragma unroll
      for (int i = 0; i < 4; i++)
        y[mt][jj][i] = acc[mt][jj][i] + bj;
    }

  // LN stats: single-pass sum + sumsq (row r = mt*16 + 4q + i)
#pragma unroll
  for (int mt = 0; mt < 2; mt++)
#pragma unroll
    for (int i = 0; i < 4; i++) {
      float s = y[mt][0][i] + y[mt][1][i] + y[mt][2][i] + y[mt][3][i];
      float ss = y[mt][0][i] * y[mt][0][i] + y[mt][1][i] * y[mt][1][i]
               + y[mt][2][i] * y[mt][2][i] + y[mt][3][i] * y[mt][3][i];
#pragma unroll
      for (int o = 1; o < 16; o <<= 1) {
        s += __shfl_xor(s, o, 64);
        ss += __shfl_xor(ss, o, 64);
      }
      if (ln == 0) { reds[16 * mt + 4 * q + i][w] = s; redq[16 * mt + 4 * q + i][w] = ss; }
    }
  __syncthreads();
  float m_[2][4], rs_[2][4], tolr[2][4];
#pragma unroll
  for (int mt = 0; mt < 2; mt++)
#pragma unroll
    for (int i = 0; i < 4; i++) {
      int r = 16 * mt + 4 * q + i;
      float S = reds[r][0] + reds[r][1] + reds[r][2] + reds[r][3];
      float Q2 = redq[r][0] + redq[r][1] + redq[r][2] + redq[r][3];
      float mm = S * (1.0f / 256.0f);
      float var = Q2 * (1.0f / 256.0f) - mm * mm;
      float rs = 1.0f / sqrtf(var + 1e-5f);
      m_[mt][i] = mm; rs_[mt][i] = rs;
      tolr[mt][i] = 1.75e-4f + 3e-6f * (4.0f + fabsf(mm) * rs);
    }

  // LIF + margin flag
  int fl[2] = {0, 0};
#pragma unroll
  for (int mt = 0; mt < 2; mt++) {
    int pi = p0 + 4 * mt + q;
    int b = pi / L_, l = pi % L_;
#pragma unroll
    for (int jj = 0; jj < 4; jj++) {
      int col = (w * 4 + jj) * 16 + ln;
      float lw = lnw[col], lb = lnb[col];
      float v = 0.0f;
#pragma unroll
      for (int t = 0; t < 4; t++) {
        float yn = (y[mt][jj][t] - m_[mt][t]) * rs_[mt][t] * lw + lb;
        v = (v + yn) * 0.5f;
        bool f = (v >= 1.0f);
        if (fabsf(v - 1.0f) < tolr[mt][t]) fl[mt] = 1;
        size_t n = ((size_t)t * B_ + b) * L_ + l;
        out[n * H_ + col] = f ? 1.0f : 0.0f;
        if (f) v = 0.0f;
      }
    }
  }
#pragma unroll
  for (int o = 1; o < 16; o <<= 1) {
    fl[0] |= __shfl_xor(fl[0], o, 64);
    fl[1] |= __shfl_xor(fl[1], o, 64);
  }
  if (ln == 0) {
    if (fl[0]) atomicOr(&pf[q], 1);
    if (fl[1]) atomicOr(&pf[4 + q], 1);
  }
  __syncthreads();
  if (tid < 8 && pf[tid]) {
    int idx = atomicAdd(cnt, 1);
    if (idx < LCAP) list[idx] = p0 + tid;
  }
}

// Exact f64 fixup, Q/K/V (unchanged).
__global__ __launch_bounds__(256)
void fixup_qkv(const float* __restrict__ xf, const float* __restrict__ wT,
               const float* __restrict__ qlnw, const float* __restrict__ qlnb,
               const float* __restrict__ klnw, const float* __restrict__ klnb,
               const float* __restrict__ vlnw, const float* __restrict__ vlnb,
               unsigned char* __restrict__ Qsp, unsigned char* __restrict__ Ksp,
               unsigned char* __restrict__ Vsp,
               const int* __restrict__ cnt, const int* __restrict__ list) {
  __shared__ float sx[4][256];     // 4 KB: the pair's 4 t-rows
  __shared__ double rsum[4][4];    // [wave][t]
  __shared__ double mv[4], rsd[4];
  const int tid = threadIdx.x;
  const int w = tid >> 6, lane = tid & 63;
  int n0 = cnt[0]; if (n0 > LCAP) n0 = LCAP;
  int n1 = cnt[1]; if (n1 > LCAP) n1 = LCAP;
  int n2 = cnt[2]; if (n2 > LCAP) n2 = LCAP;
  int ntot = n0 + n1 + n2;
  for (int e = blockIdx.x; e < ntot; e += gridDim.x) {
    int mat, ei;
    if (e < n0) { mat = 0; ei = e; }
    else if (e < n0 + n1) { mat = 1; ei = e - n0; }
    else { mat = 2; ei = e - n0 - n1; }
    const float* wTm = wT + (size_t)mat * 65536;
    const float* lnw = (mat == 0) ? qlnw : (mat == 1) ? klnw : vlnw;
    const float* lnb = (mat == 0) ? qlnb : (mat == 1) ? klnb : vlnb;
    unsigned char* spk = (mat == 0) ? Qsp : (mat == 1) ? Ksp : Vsp;
    int pi = list[mat * LCAP + ei];
    int b = pi / L_, l = pi % L_;

    // stage: wave w loads t-row w (64 lanes x float4 = 256 floats, coalesced)
    {
      size_t nrow = ((size_t)w * B_ + b) * L_ + l;
      float4 v = *(const float4*)(xf + nrow * H_ + lane * 4);
      *(float4*)&sx[w][lane * 4] = v;
    }
    __syncthreads();

    double acc[4] = {0.0, 0.0, 0.0, 0.0};
    for (int k = 0; k < 256; k++) {
      double wv = (double)wTm[k * 256 + tid];
      acc[0] += (double)sx[0][k] * wv;
      acc[1] += (double)sx[1][k] * wv;
      acc[2] += (double)sx[2][k] * wv;
      acc[3] += (double)sx[3][k] * wv;
    }
#pragma unroll
    for (int t = 0; t < 4; t++) {
      double s = acc[t];
#pragma unroll
      for (int o = 1; o < 64; o <<= 1) s += __shfl_xor(s, o, 64);
      if (lane == 0) rsum[w][t] = s;
    }
    __syncthreads();
    if (tid < 4) mv[tid] = (rsum[0][tid] + rsum[1][tid] + rsum[2][tid] + rsum[3][tid]) * (1.0 / 256.0);
    __syncthreads();
#pragma unroll
    for (int t = 0; t < 4; t++) {
      double d = acc[t] - mv[t];
      double ss = d * d;
#pragma unroll
      for (int o = 1; o < 64; o <<= 1) ss += __shfl_xor(ss, o, 64);
      if (lane == 0) rsum[w][t] = ss;
    }
    __syncthreads();
    if (tid < 4) {
      double var = (rsum[0][tid] + rsum[1][tid] + rsum[2][tid] + rsum[3][tid]) * (1.0 / 256.0);
      rsd[tid] = 1.0 / sqrt(var + 1e-5);
    }
    __syncthreads();
    double lw = (double)lnw[tid], lb = (double)lnb[tid];
    int head = tid >> 7, d = tid & 127;
    double v = 0.0;
#pragma unroll
    for (int t = 0; t < 4; t++) {
      double yn = (acc[t] - mv[t]) * rsd[t] * lw + lb;
      v = (v + yn) * 0.5;
      bool f = (v >= 1.0);
      spk[((((size_t)t * B_ + b) * NH_ + head) * L_ + l) * DH_ + d] = f ? (unsigned char)1 : (unsigned char)0;
      if (f) v = 0.0;
    }
    __syncthreads();   // sx/rsum reuse fence before next pair
  }
}

// Exact f64 fixup, proj (unchanged).
__global__ __launch_bounds__(256)
void fixup_proj(const unsigned char* __restrict__ xs, const float* __restrict__ wT,
                const float* __restrict__ bias,
                const float* __restrict__ lnw, const float* __restrict__ lnb,
                float* __restrict__ out,
                const int* __restrict__ cnt, const int* __restrict__ list) {
  __shared__ float sx[4][256];
  __shared__ double rsum[4][4];
  __shared__ double mv[4], rsd[4];
  const int tid = threadIdx.x;
  const int w = tid >> 6, lane = tid & 63;
  int n = *cnt; if (n > LCAP) n = LCAP;
  for (int e = blockIdx.x; e < n; e += gridDim.x) {
    int pi = list[e];
    int b = pi / L_, l = pi % L_;
    size_t nrowW = ((size_t)w * B_ + b) * L_ + l;

    // stage: wave w loads t-row w (64 lanes x uchar4 = 256 u8, converted)
    {
      uchar4 u = *(const uchar4*)(xs + nrowW * H_ + lane * 4);
      float4 v = make_float4((float)u.x, (float)u.y, (float)u.z, (float)u.w);
      *(float4*)&sx[w][lane * 4] = v;
    }
    __syncthreads();

    double acc[4];
    double bj = (double)bias[tid];
#pragma unroll
    for (int t = 0; t < 4; t++) acc[t] = bj;
    for (int k = 0; k < 256; k++) {
      double wv = (double)wT[k * 256 + tid];
      acc[0] += (double)sx[0][k] * wv;
      acc[1] += (double)sx[1][k] * wv;
      acc[2] += (double)sx[2][k] * wv;
      acc[3] += (double)sx[3][k] * wv;
    }
#pragma unroll
    for (int t = 0; t < 4; t++) {
      double s = acc[t];
#pragma unroll
      for (int o = 1; o < 64; o <<= 1) s += __shfl_xor(s, o, 64);
      if (lane == 0) rsum[w][t] = s;
    }
    __syncthreads();
    if (tid < 4) mv[tid] = (rsum[0][tid] + rsum[1][tid] + rsum[2][tid] + rsum[3][tid]) * (1.0 / 256.0);
    __syncthreads();
#pragma unroll
    for (int t = 0; t < 4; t++) {
      double d = acc[t] - mv[t];
      double ss = d * d;
#pragma unroll
      for (int o = 1; o < 64; o <<= 1) ss += __shfl_xor(ss, o, 64);
      if (lane == 0) rsum[w][t] = ss;
    }
    __syncthreads();
    if (tid < 4) {
      double var = (rsum[0][tid] + rsum[1][tid] + rsum[2][tid] + rsum[3][tid]) * (1.0 / 256.0);
      rsd[tid] = 1.0 / sqrt(var + 1e-5);
    }
    __syncthreads();
    double lw = (double)lnw[tid], lb = (double)lnb[tid];
    double v = 0.0;
#pragma unroll
    for (int t = 0; t < 4; t++) {
      double yn = (acc[t] - mv[t]) * rsd[t] * lw + lb;
      v = (v + yn) * 0.5;
      bool f = (v >= 1.0);
      out[(((size_t)t * B_ + b) * L_ + l) * H_ + tid] = f ? 1.0f : 0.0f;
      if (f) v = 0.0;
    }
    __syncthreads();
  }
}

// V spikes [slab][m<200][d] u8 -> Vt [slab][d][m<224] u8, zero-padded m>=200.
__global__ __launch_bounds__(256)
void vt_prep(const unsigned char* __restrict__ Vs, unsigned char* __restrict__ Vt) {
  const int slab = blockIdx.x;
  const int w = threadIdx.x >> 6, lane = threadIdx.x & 63;
  const unsigned char* src = Vs + (size_t)slab * (L_ * DH_);
  unsigned char* dst = Vt + (size_t)slab * (DH_ * 224);
  for (int d = w; d < DH_; d += 4) {
    for (int mb = 0; mb < 4; mb++) {
      int m = mb * 64 + lane;
      unsigned char v = 0;
      if (m < L_) v = src[(size_t)m * DH_ + d];
      if (m < 224) dst[(size_t)d * 224 + m] = v;
    }
  }
}

// MFMA attention + attn-LIF(v_th=0.5). Exact.
// R14: QK^T on the i8 matrix pipe - Q/K spikes are {0,1} BYTES, so
// mfma_i32_16x16x64_i8 consumes them raw: zero unpack VALU (was ~480
// ops/block/t), half the QK MFMAs (K=64 vs 32), 16B loads (was 4x8B+unpack).
// Dots <=128: exact in i32; (float)i32 exact; bf16 truncation exact
// (ints <=256) -> sS bit-identical to the bf16 path. PV unchanged (its
// A-operand can be 128 which overflows i8).
// i8 A-frag layout: row=lane&15, k=(lane>>4)*16+byte (analog of verified
// bf16 k=(lane>>4)*8+j); C/D layout shape-determined, dtype-independent.
__global__ __launch_bounds__(256)
void attn_mfma(const unsigned char* __restrict__ Qs, const unsigned char* __restrict__ Ks,
               const unsigned char* __restrict__ Vt, unsigned char* __restrict__ S2) {
  __shared__ unsigned short sS[32 * 232];
  const int tid = threadIdx.x;
  const int w = tid >> 6, lane = tid & 63;
  const int quad = lane >> 4, ln = lane & 15;
  const int bid = blockIdx.x;
  const int lt = bid % 7;
  const int head = (bid / 7) & 1;
  const int b = bid / 14;
  const int l0 = lt * 32;

  for (int i = tid; i < 32 * 232; i += 256) sS[i] = 0;

  float vmem[2][2][4];
#pragma unroll
  for (int di = 0; di < 2; di++)
#pragma unroll
    for (int ls = 0; ls < 2; ls++)
#pragma unroll
      for (int r = 0; r < 4; r++) vmem[di][ls][r] = 0.f;

  __syncthreads();

  for (int t = 0; t < T_; t++) {
    const int slab = (t * B_ + b) * NH_ + head;
    const unsigned char* qb = Qs + (size_t)slab * (L_ * DH_) + (size_t)l0 * DH_;
    const unsigned char* kb = Ks + (size_t)slab * (L_ * DH_);

    // i8 Q fragments: row = ls*16+ln, k-halves ks2=0,1; 16B per lane.
    i32x4 aq[2][2];
#pragma unroll
    for (int ls = 0; ls < 2; ls++)
#pragma unroll
      for (int ks2 = 0; ks2 < 2; ks2++)
        aq[ls][ks2] = *(const i32x4*)(qb + (size_t)(ls * 16 + ln) * DH_ + ks2 * 64 + quad * 16);

#pragma unroll
    for (int i = 0; i < 4; i++) {
      int nt = w + 4 * i;
      if (nt < 13) {
        i32x4 bk[2];
#pragma unroll
        for (int ks2 = 0; ks2 < 2; ks2++)
          bk[ks2] = *(const i32x4*)(kb + (size_t)(nt * 16 + ln) * DH_ + ks2 * 64 + quad * 16);
#pragma unroll
        for (int ls = 0; ls < 2; ls++) {
          i32x4 acci = {0, 0, 0, 0};
          acci = MFMA_I8(aq[ls][0], bk[0], acci);
          acci = MFMA_I8(aq[ls][1], bk[1], acci);
#pragma unroll
          for (int r = 0; r < 4; r++)
            sS[(ls * 16 + quad * 4 + r) * 232 + nt * 16 + ln] =
                (unsigned short)(__float_as_uint((float)acci[r]) >> 16);
        }
      }
    }
    __syncthreads();

    const unsigned char* vb = Vt + (size_t)slab * (DH_ * 224);
    f32x4 a2[2][2];
#pragma unroll
    for (int di = 0; di < 2; di++)
#pragma unroll
      for (int ls = 0; ls < 2; ls++) { f32x4 z = {0.f, 0.f, 0.f, 0.f}; a2[di][ls] = z; }

#pragma unroll
    for (int ks = 0; ks < 7; ks++) {
      short8_t s0 = *(const short8_t*)&sS[(0 * 16 + ln) * 232 + ks * 32 + quad * 8];
      short8_t s1 = *(const short8_t*)&sS[(1 * 16 + ln) * 232 + ks * 32 + quad * 8];
#pragma unroll
      for (int di = 0; di < 2; di++) {
        int dt = w + 4 * di;
        short8_t bv = unpack_bf16(*(const uint2*)(vb + (size_t)(dt * 16 + ln) * 224 + ks * 32 + quad * 8));
        a2[di][0] = MFMA_BF16(s0, bv, a2[di][0]);
        a2[di][1] = MFMA_BF16(s1, bv, a2[di][1]);
      }
    }

#pragma unroll
    for (int di = 0; di < 2; di++)
#pragma unroll
      for (int ls = 0; ls < 2; ls++)
#pragma unroll
        for (int r = 0; r < 4; r++) {
          float y = a2[di][ls][r] * 0.125f;
          float v = (vmem[di][ls][r] + y) * 0.5f;
          bool f = (v >= 0.5f);
          int l = l0 + ls * 16 + quad * 4 + r;
          if (l < L_)
            S2[(((size_t)t * B_ + b) * L_ + l) * H_ + head * DH_ + (w + 4 * di) * 16 + ln] =
                f ? (unsigned char)1 : (unsigned char)0;
          vmem[di][ls][r] = f ? 0.f : v;
        }
    __syncthreads();
  }
}

extern "C" void kernel_launch(void* const* d_in, const int* in_sizes, int n_in,
                              void* d_out, int out_size, void* d_ws, size_t ws_size,
                              hipStream_t stream) {
  (void)in_sizes; (void)n_in; (void)out_size; (void)ws_size;
  const float* x    = (const float*)d_in[0];
  const float* qw   = (const float*)d_in[1];
  const float* qlnw = (const float*)d_in[2];
  const float* qlnb = (const float*)d_in[3];
  const float* kw   = (const float*)d_in[4];
  const float* klnw = (const float*)d_in[5];
  const float* klnb = (const float*)d_in[6];
  const float* vw   = (const float*)d_in[7];
  const float* vlnw = (const float*)d_in[8];
  const float* vlnb = (const float*)d_in[9];
  const float* pw   = (const float*)d_in[10];
  const float* pb   = (const float*)d_in[11];
  const float* plnw = (const float*)d_in[12];
  const float* plnb = (const float*)d_in[13];

  char* ws = (char*)d_ws;
  const size_t SPK = (size_t)T_ * B_ * NH_ * L_ * DH_;     // 13,107,200
  short* wf  = (short*)ws;                                  // 1,572,864 B
  float* wT  = (float*)(ws + 1572864);                      // 1,048,576 B
  int*  cnt  = (int*)(ws + 2621440);                        // 16 B
  int*  list = (int*)(ws + 2621696);                        // 204,800 B
  unsigned char* Qsp = (unsigned char*)(ws + 2826496);
  unsigned char* Ksp = Qsp + SPK;
  unsigned char* Vsp = Ksp + SPK;
  unsigned char* S2  = Vsp;                                 // alias after vt_prep
  unsigned char* Vt  = Vsp + SPK;                           // ~54.2 MiB total

  hipLaunchKernelGGL(pack_w, dim3(1408), dim3(256), 0, stream, qw, kw, vw, pw, wf, wT, cnt);

  hipLaunchKernelGGL(gemm_qkv, dim3(1600), dim3(256), 0, stream,
                     x, wf, qlnw, qlnb, klnw, klnb, vlnw, vlnb, Qsp, Ksp, Vsp, cnt, list);

  hipLaunchKernelGGL(fixup_qkv, dim3(2048), dim3(256), 0, stream,
                     x, wT, qlnw, qlnb, klnw, klnb, vlnw, vlnb, Qsp, Ksp, Vsp, cnt, list);

  hipLaunchKernelGGL(vt_prep, dim3(512), dim3(256), 0, stream, Vsp, Vt);
  hipLaunchKernelGGL(attn_mfma, dim3(896), dim3(256), 0, stream, Qsp, Ksp, Vt, S2);

  hipLaunchKernelGGL(gemm_proj, dim3(1600), dim3(256), 0, stream,
                     S2, wf + 589824, pb, plnw, plnb, (float*)d_out, cnt + 3, list + 3 * LCAP);
  hipLaunchKernelGGL(fixup_proj, dim3(2048), dim3(256), 0, stream,
                     S2, wT + 196608, pb, plnw, plnb, (float*)d_out, cnt + 3, list + 3 * LCAP);
}